// Round 11
// baseline (1308.557 us; speedup 1.0000x reference)
//
#include <hip/hip_runtime.h>
#include <hip/hip_cooperative_groups.h>
#include <math.h>

namespace cg = cooperative_groups;

// Problem constants (fixed by the reference).
#define Bsz 64
#define Ssz 14
#define Isz 32
#define Csz 10
#define Dsz 16
#define Nsz (Ssz*Ssz*Isz)   // 6272
#define EPSF 1e-9f

#define CH   640            // em chunk: n's per block (== block size)
#define NCH  10             // chunks; chunk 9 has 512 valid n
#define PST  36             // prm row stride: mean16 | invd16 | K | pad
#define BC   (Bsz*Csz)      // 640
#define CPL  (BC*33)        // partC chunk plane: 21120 floats

// ---------------------------------------------------------------------------
// DPP wave64 sum (VALU-only). Total lands in lane 63. Validated r1-r10.
// ---------------------------------------------------------------------------
template<int CTRL, int RMASK>
__device__ __forceinline__ float dpp_add(float x) {
    int y = __builtin_amdgcn_update_dpp(0, __float_as_int(x), CTRL, RMASK, 0xf, true);
    return x + __int_as_float(y);
}
__device__ __forceinline__ float wave_sum64(float x) {
    x = dpp_add<0x111, 0xf>(x);
    x = dpp_add<0x112, 0xf>(x);
    x = dpp_add<0x114, 0xf>(x);
    x = dpp_add<0x118, 0xf>(x);
    x = dpp_add<0x142, 0xa>(x);
    x = dpp_add<0x143, 0xc>(x);
    return x;
}

// ===========================================================================
// Shared phase bodies (r10-validated, verbatim) — used by BOTH the cooperative
// kernel and the fallback multi-dispatch kernels.
// ===========================================================================

// m0: iteration-0 M-step, uniform rr (wgt = act/C). Wave-per-class, W from
// global, DPP reduce, no LDS/barriers. Block (0,0) also builds Wt[c][i][16].
__device__ __forceinline__ void m0_phase(
    const float* __restrict__ pose, const float* __restrict__ act,
    const float* __restrict__ w, float* __restrict__ wt,
    float* __restrict__ partC, int b, int chunk, int tid, int wv, int lane)
{
    if (b == 0 && chunk == 0) {
        for (int t = tid; t < Csz*Isz*Dsz; t += 640) {
            const int cc = t >> 9, rem = t & 511, i = rem >> 4, q = rem & 15;
            wt[t] = w[(i*Csz + cc)*Dsz + q];
        }
    }
    const int c = wv;
    const float4* wp = reinterpret_cast<const float4*>(
        w + ((size_t)(lane & 31)*Csz + c)*Dsz);
    float4 q0 = wp[0], q1 = wp[1], q2 = wp[2], q3 = wp[3];
    float W16[16] = {q0.x,q0.y,q0.z,q0.w, q1.x,q1.y,q1.z,q1.w,
                     q2.x,q2.y,q2.z,q2.w, q3.x,q3.y,q3.z,q3.w};

    const int base = chunk*CH;
    const float* poseb = pose + (size_t)b*Nsz*Dsz;
    const float* actb  = act  + (size_t)b*Nsz;

    float s0 = 0.f, s1[16], s2[16];
#pragma unroll
    for (int d = 0; d < 16; ++d) { s1[d] = 0.f; s2[d] = 0.f; }

    for (int k = 0; k < CH; k += 64) {
        const int n = base + k + lane;
        if (n < Nsz) {
            const float4* pp = reinterpret_cast<const float4*>(poseb + (size_t)n*Dsz);
            const int hw = n >> 5, wc2 = hw % Ssz, hr2 = hw / Ssz;
            const float chh = (hr2+0.5f)*(1.f/Ssz), cww = (wc2+0.5f)*(1.f/Ssz);
            const float wgt = actb[n]*(1.f/Csz);
            s0 += wgt;
#pragma unroll
            for (int pr = 0; pr < 4; ++pr) {
                const float4 pv = pp[pr];
#pragma unroll
                for (int r = 0; r < 4; ++r) {
                    float vv = pv.x*W16[0*4+r] + pv.y*W16[1*4+r]
                             + pv.z*W16[2*4+r] + pv.w*W16[3*4+r];
                    if (pr == 0 && r == 0) vv += chh;
                    if (pr == 0 && r == 1) vv += cww;
                    const float wvv = wgt*vv;
                    s1[pr*4+r] += wvv;
                    s2[pr*4+r] += wvv*vv;
                }
            }
        }
    }
    s0 = wave_sum64(s0);
#pragma unroll
    for (int d = 0; d < 16; ++d) { s1[d] = wave_sum64(s1[d]); s2[d] = wave_sum64(s2[d]); }
    if (lane == 63) {
        float* pt = partC + (size_t)chunk*CPL + (size_t)(b*Csz + c)*33;
        pt[0] = s0;
#pragma unroll
        for (int d = 0; d < 16; ++d) { pt[1+d] = s1[d]; pt[17+d] = s2[d]; }
    }
}

// em: E (thread-per-n; W from transposed global Wt, coalesced dwordx4; prm
// staged to LDS broadcasts) + barrier + M (wave-per-class, Wt hoisted, DPP).
__device__ __forceinline__ void em_phase(
    const float* __restrict__ pose, const float* __restrict__ act,
    const float* __restrict__ wt, const float* __restrict__ prm,
    float* __restrict__ partC, float (*rr)[CH], float (*prmL)[PST],
    int b, int chunk, int tid, int wv, int lane)
{
    // stage prm[b] -> LDS (broadcast-read in E; also makes coherence explicit)
    if (tid < Csz*33) {
        const int c2 = tid / 33, j = tid - c2*33;
        prmL[c2][j] = prm[(size_t)(b*Csz + c2)*PST + j];
    }
    __syncthreads();

    const int base = chunk*CH;
    const float* poseb = pose + (size_t)b*Nsz*Dsz;

    {   // ---- E phase: one n per thread ----
        const int n = base + tid;
        if (n < Nsz) {
            const float4* pp = reinterpret_cast<const float4*>(poseb + (size_t)n*Dsz);
            float4 a0 = pp[0], a1 = pp[1], a2 = pp[2], a3 = pp[3];
            float p[16] = {a0.x,a0.y,a0.z,a0.w, a1.x,a1.y,a1.z,a1.w,
                           a2.x,a2.y,a2.z,a2.w, a3.x,a3.y,a3.z,a3.w};
            const int i = tid & 31;
            const int hw = n >> 5;
            const int wc = hw % Ssz, hr = hw / Ssz;
            const float chh = (hr+0.5f)*(1.0f/Ssz), cww = (wc+0.5f)*(1.0f/Ssz);
            const float a = act[(size_t)b*Nsz + n];
            float zz[Csz];
#pragma unroll
            for (int c = 0; c < Csz; ++c) {
                const float4* wp4 = reinterpret_cast<const float4*>(
                    wt + ((size_t)c*Isz + i)*Dsz);
                float4 w0 = wp4[0], w1 = wp4[1], w2 = wp4[2], w3 = wp4[3];
                const float W16[16] = {w0.x,w0.y,w0.z,w0.w, w1.x,w1.y,w1.z,w1.w,
                                       w2.x,w2.y,w2.z,w2.w, w3.x,w3.y,w3.z,w3.w};
                float quad = 0.f;
#pragma unroll
                for (int pr = 0; pr < 4; ++pr) {
                    const float4 m4 = *reinterpret_cast<const float4*>(&prmL[c][pr*4]);
                    const float4 g4 = *reinterpret_cast<const float4*>(&prmL[c][16+pr*4]);
                    float v0 = p[pr*4]*W16[0] + p[pr*4+1]*W16[4] + p[pr*4+2]*W16[8]  + p[pr*4+3]*W16[12];
                    float v1 = p[pr*4]*W16[1] + p[pr*4+1]*W16[5] + p[pr*4+2]*W16[9]  + p[pr*4+3]*W16[13];
                    float v2 = p[pr*4]*W16[2] + p[pr*4+1]*W16[6] + p[pr*4+2]*W16[10] + p[pr*4+3]*W16[14];
                    float v3 = p[pr*4]*W16[3] + p[pr*4+1]*W16[7] + p[pr*4+2]*W16[11] + p[pr*4+3]*W16[15];
                    if (pr == 0) { v0 += chh; v1 += cww; }
                    const float d0 = v0 - m4.x, d1 = v1 - m4.y, d2 = v2 - m4.z, d3 = v3 - m4.w;
                    quad += d0*d0*g4.x + d1*d1*g4.y + d2*d2*g4.z + d3*d3*g4.w;
                }
                zz[c] = prmL[c][32] - quad;
            }
            float zmax = zz[0];
#pragma unroll
            for (int c = 1; c < Csz; ++c) zmax = fmaxf(zmax, zz[c]);
            float zsum = 0.f;
#pragma unroll
            for (int c = 0; c < Csz; ++c) { zz[c] = __expf(zz[c] - zmax); zsum += zz[c]; }
            const float sc = __fdividef(a, zsum);
#pragma unroll
            for (int c = 0; c < Csz; ++c) rr[c][tid] = zz[c]*sc;
        }
    }
    __syncthreads();

    // ---- M phase: wave = class; W16 from Wt (coalesced, i = lane&31) ----
    const int c = wv;
    const float4* wp4 = reinterpret_cast<const float4*>(
        wt + ((size_t)c*Isz + (lane & 31))*Dsz);
    float4 q0 = wp4[0], q1 = wp4[1], q2 = wp4[2], q3 = wp4[3];
    float W16[16] = {q0.x,q0.y,q0.z,q0.w, q1.x,q1.y,q1.z,q1.w,
                     q2.x,q2.y,q2.z,q2.w, q3.x,q3.y,q3.z,q3.w};

    float s0 = 0.f, s1[16], s2[16];
#pragma unroll
    for (int d = 0; d < 16; ++d) { s1[d] = 0.f; s2[d] = 0.f; }

    for (int k = 0; k < CH; k += 64) {
        const int nl = k + lane;
        const int n = base + nl;
        if (n < Nsz) {
            const float4* pp = reinterpret_cast<const float4*>(poseb + (size_t)n*Dsz);
            const int hw = n >> 5;
            const int wc2 = hw % Ssz, hr2 = hw / Ssz;
            const float chh = (hr2+0.5f)*(1.0f/Ssz), cww = (wc2+0.5f)*(1.0f/Ssz);
            const float wgt = rr[c][nl];
            s0 += wgt;
#pragma unroll
            for (int pr = 0; pr < 4; ++pr) {
                const float4 pv = pp[pr];
#pragma unroll
                for (int r = 0; r < 4; ++r) {
                    float vv = pv.x*W16[0*4+r] + pv.y*W16[1*4+r]
                             + pv.z*W16[2*4+r] + pv.w*W16[3*4+r];
                    if (pr == 0 && r == 0) vv += chh;
                    if (pr == 0 && r == 1) vv += cww;
                    const float wvv = wgt*vv;
                    s1[pr*4+r] += wvv;
                    s2[pr*4+r] += wvv*vv;
                }
            }
        }
    }
    s0 = wave_sum64(s0);
#pragma unroll
    for (int d = 0; d < 16; ++d) { s1[d] = wave_sum64(s1[d]); s2[d] = wave_sum64(s2[d]); }
    if (lane == 63) {
        float* pt = partC + (size_t)chunk*CPL + (size_t)(b*Csz + c)*33;
        pt[0] = s0;
#pragma unroll
        for (int d = 0; d < 16; ++d) { pt[1+d] = s1[d]; pt[17+d] = s2[d]; }
    }
}

// fin: one WAVE per (b,c). Lane j<33 sums partC[ch][bc][j] over 10 chunks;
// shuffles compute mean/var; writes prm (mid) or outputs (final).
__device__ __forceinline__ void fin_wave(
    const float* __restrict__ partC, const float* __restrict__ beta_v,
    const float* __restrict__ beta_a, float* __restrict__ prmOut,
    float* __restrict__ out, float inv_temp, int bc, int j)
{
    const int c = bc % Csz;
    float S = 0.f;
    if (j < 33) {
        const float* pb = partC + (size_t)bc*33 + j;
#pragma unroll
        for (int ch = 0; ch < NCH; ++ch) S += pb[(size_t)ch*CPL];
    }
    const float S0 = __shfl(S, 0);
    const float rS0 = 1.f / S0;

    const int src = (j >= 1 && j <= 16) ? (16 + j) : 0;
    const float S2d = __shfl(S, src);
    float mn = 0.f, lg = 0.f, iv = 0.f;
    if (j >= 1 && j <= 16) {
        mn = S * rS0;
        const float var = fmaxf(S2d * rS0 - mn*mn, 0.f);
        iv = 1.f/(2.f*var + EPSF);
        lg = __logf(sqrtf(var) + EPSF);
    }
    float sumlog = lg;
#pragma unroll
    for (int m = 32; m >= 1; m >>= 1) sumlog += __shfl_xor(sumlog, m);

    if (out) {
        if (j >= 1 && j <= 16) out[(size_t)bc*Dsz + (j-1)] = mn;
        if (j == 0) {
            const float cost = S0*(16.f*beta_v[c] + sumlog);
            out[(size_t)Bsz*Csz*Dsz + bc] = 1.f/(1.f + __expf(-inv_temp*(beta_a[c] - cost)));
        }
    } else {
        float* o = prmOut + (size_t)bc*PST;
        if (j >= 1 && j <= 16) { o[j-1] = mn; o[16 + (j-1)] = iv; }
        if (j == 0) {
            const float cost = S0*(16.f*beta_v[c] + sumlog);
            const float oact = 1.f/(1.f + __expf(-inv_temp*(beta_a[c] - cost)));
            o[32] = __logf(oact + EPSF) - sumlog;
        }
    }
}

// ===========================================================================
// Cooperative mega-kernel: m0 -> fin0 -> em1 -> fin1 -> em2 -> fin2, with
// grid.sync between phases. LDS 27 KB, launch_bounds(640,8) caps VGPR at 64
// (r10's em fits exactly) -> 3 blocks/CU -> 768 slots >= 640 blocks.
// ===========================================================================
__global__ __launch_bounds__(640, 8) void coop_kernel(
    const float* __restrict__ pose, const float* __restrict__ act,
    const float* __restrict__ w, const float* __restrict__ beta_v,
    const float* __restrict__ beta_a, float* __restrict__ wt,
    float* __restrict__ prm, float* __restrict__ partC,
    float* __restrict__ out)
{
    cg::grid_group gg = cg::this_grid();
    const int b = blockIdx.x, chunk = blockIdx.y;
    const int tid = threadIdx.x, wv = tid >> 6, lane = tid & 63;

    __shared__ float rr[Csz][CH];       // 25600 B
    __shared__ float prmL[Csz][PST];    //  1440 B

    m0_phase(pose, act, w, wt, partC, b, chunk, tid, wv, lane);
    gg.sync();
    if (chunk == 0) fin_wave(partC, beta_v, beta_a, prm, nullptr, 1.0f, b*Csz + wv, lane);
    gg.sync();
    em_phase(pose, act, wt, prm, partC, rr, prmL, b, chunk, tid, wv, lane);
    gg.sync();
    if (chunk == 0) fin_wave(partC, beta_v, beta_a, prm, nullptr, 2.0f, b*Csz + wv, lane);
    gg.sync();
    em_phase(pose, act, wt, prm, partC, rr, prmL, b, chunk, tid, wv, lane);
    gg.sync();
    if (chunk == 0) fin_wave(partC, beta_v, beta_a, nullptr, out, 3.0f, b*Csz + wv, lane);
}

// ===========================================================================
// Fallback kernels (r10-validated pipeline, same phase bodies).
// ===========================================================================
__global__ __launch_bounds__(640) void m0_kernel(
    const float* __restrict__ pose, const float* __restrict__ act,
    const float* __restrict__ w, float* __restrict__ wt,
    float* __restrict__ partC)
{
    m0_phase(pose, act, w, wt, partC, blockIdx.x, blockIdx.y,
             threadIdx.x, threadIdx.x >> 6, threadIdx.x & 63);
}

__global__ __launch_bounds__(640) void em_kernel(
    const float* __restrict__ pose, const float* __restrict__ act,
    const float* __restrict__ wt, const float* __restrict__ prm,
    float* __restrict__ partC)
{
    __shared__ float rr[Csz][CH];
    __shared__ float prmL[Csz][PST];
    em_phase(pose, act, wt, prm, partC, rr, prmL, blockIdx.x, blockIdx.y,
             threadIdx.x, threadIdx.x >> 6, threadIdx.x & 63);
}

__global__ __launch_bounds__(64) void fin_kernel(
    const float* __restrict__ partC, const float* __restrict__ beta_v,
    const float* __restrict__ beta_a, float* __restrict__ prmOut,
    float* __restrict__ out, float inv_temp)
{
    fin_wave(partC, beta_v, beta_a, prmOut, out, inv_temp,
             blockIdx.x, threadIdx.x);
}

// ---------------------------------------------------------------------------
// Launch: try ONE cooperative dispatch; on any launch error fall back to the
// validated 6-dispatch pipeline. Workspace: partC 211200 + prm 23040 + Wt
// 5120 floats = 957 KB. Single partC/prm buffers are safe in both paths:
// every producer/consumer pair is separated by a grid.sync (coop) or by
// dispatch ordering (fallback).
// ---------------------------------------------------------------------------
extern "C" void kernel_launch(void* const* d_in, const int* in_sizes, int n_in,
                              void* d_out, int out_size, void* d_ws, size_t ws_size,
                              hipStream_t stream)
{
    (void)in_sizes; (void)n_in; (void)out_size; (void)ws_size;
    const float* pose = (const float*)d_in[0];
    const float* act  = (const float*)d_in[1];
    const float* w    = (const float*)d_in[2];
    const float* bv   = (const float*)d_in[3];
    const float* ba   = (const float*)d_in[4];
    float* out = (float*)d_out;

    float* partC = (float*)d_ws;                       // [10][640][33]
    float* prm   = partC + (size_t)NCH*CPL;            // [640][36]
    float* wtT   = prm + (size_t)BC*PST;               // [10][32][16]

    void* args[] = {(void*)&pose, (void*)&act, (void*)&w, (void*)&bv, (void*)&ba,
                    (void*)&wtT, (void*)&prm, (void*)&partC, (void*)&out};
    hipError_t e = hipLaunchCooperativeKernel(
        reinterpret_cast<void*>(coop_kernel), dim3(Bsz, NCH), dim3(640),
        args, 0, stream);

    if (e != hipSuccess) {
        (void)hipGetLastError();   // clear the error, use the proven pipeline
        m0_kernel <<<dim3(Bsz, NCH), 640, 0, stream>>>(pose, act, w, wtT, partC);
        fin_kernel<<<BC,              64, 0, stream>>>(partC, bv, ba, prm, nullptr, 1.0f);
        em_kernel <<<dim3(Bsz, NCH), 640, 0, stream>>>(pose, act, wtT, prm, partC);
        fin_kernel<<<BC,              64, 0, stream>>>(partC, bv, ba, prm, nullptr, 2.0f);
        em_kernel <<<dim3(Bsz, NCH), 640, 0, stream>>>(pose, act, wtT, prm, partC);
        fin_kernel<<<BC,              64, 0, stream>>>(partC, bv, ba, nullptr, out, 3.0f);
    }
}